// Round 9
// baseline (213.738 us; speedup 1.0000x reference)
//
#include <hip/hip_runtime.h>
#include <math.h>

#define N_  16
#define C_  128
#define T_  16384
#define K_  64
#define KG_ 73
#define CT  512           // t-chunk per block -> 512 blocks = 2 blocks/CU
#define NCH 32            // chunks per n
#define EPSN 1e-12f
#define P1  72            // xb pitch (bf16): 36 dwords -> 8 bank-groups for b128 reads
#define P2  72            // st pitch (bf16)

typedef __bf16 bf16x4v __attribute__((ext_vector_type(4)));
typedef __bf16 bf16x8v __attribute__((ext_vector_type(8)));
typedef float  f32x4v  __attribute__((ext_vector_type(4)));

#define MFMA(a, b, c) __builtin_amdgcn_mfma_f32_16x16x32_bf16((a), (b), (c), 0, 0, 0)

// ---------------------------------------------------------------------------
// Kernel 1: fused normalize -> logits (MFMA) -> softmax -> VLAD (MFMA) ->
//           per-chunk partials (NO atomics).
// R7 change: paired prefetch (pfA+pfB = 2 tiles per issue). Per x-row, a
// wave now requests 512 B contiguous per issue instead of 256 B — doubles
// the DRAM burst length of the 64KB-strided row reads, which R4/R6 nulls
// isolated as the remaining candidate for k_main's gap above the BW floor.
// Tile math, barriers, LDS layout bit-identical to the verified R6 kernel.
// ---------------------------------------------------------------------------

// One tile body: stage from PF, (optionally) issue next-pair prefetch,
// GEMM1+Gram from LDS, softmax, st write, GEMM2. p flipped at end.
#define TILE_BODY(PF, DO_PREFETCH)                                               \
    {                                                                            \
        _Pragma("unroll")                                                        \
        for (int r = 0; r < 8; ++r) {                                            \
            bf16x4v v = { (__bf16)PF[r].x, (__bf16)PF[r].y,                      \
                          (__bf16)PF[r].z, (__bf16)PF[r].w };                    \
            *(bf16x4v*)&xb[p][(cst + 16 * r) * P1 + 4 * t4] = v;                 \
        }                                                                        \
        __syncthreads();               /* barrier A: xb[p] visible */            \
        if (DO_PREFETCH && ip < 3) {                                             \
            const int tb = t0 + (2 * ip + 2) * 64;                               \
            _Pragma("unroll")                                                    \
            for (int r = 0; r < 8; ++r) {                                        \
                pfA[r] = *(const float4*)(xbase + (size_t)r * 16 * T_ + tb);     \
                pfB[r] = *(const float4*)(xbase + (size_t)r * 16 * T_ + tb + 64);\
            }                                                                    \
        }                                                                        \
        f32x4v acc1[5];                                                          \
        _Pragma("unroll")                                                        \
        for (int i = 0; i < 5; ++i) acc1[i] = (f32x4v){0.f, 0.f, 0.f, 0.f};      \
        f32x4v gr = (f32x4v){0.f, 0.f, 0.f, 0.f};                                \
        _Pragma("unroll")                                                        \
        for (int ks = 0; ks < 4; ++ks) {                                         \
            bf16x8v af;                                                          \
            _Pragma("unroll")                                                    \
            for (int j = 0; j < 8; ++j)                                          \
                af[j] = xb[p][(32 * ks + 8 * q + j) * P1 + tA];                  \
            gr = MFMA(af, af, gr);                                               \
            _Pragma("unroll")                                                    \
            for (int nt = 0; nt < 5; ++nt)                                       \
                acc1[nt] = MFMA(af, wf[nt][ks], acc1[nt]);                       \
        }                                                                        \
        float rn[4];                                                             \
        _Pragma("unroll")                                                        \
        for (int r = 0; r < 4; ++r) {                                            \
            const float ss = __int_as_float(                                     \
                __builtin_amdgcn_ds_bpermute((20 * q + r) << 2,                  \
                                             __float_as_int(gr[r])));            \
            rn[r] = 1.f / fmaxf(sqrtf(ss), EPSN);                                \
        }                                                                        \
        float e[5][4];                                                           \
        float d[4] = {0.f, 0.f, 0.f, 0.f};                                       \
        _Pragma("unroll")                                                        \
        for (int nt = 0; nt < 5; ++nt) {                                         \
            const bool valid = (16 * nt + l15) < KG_;                            \
            _Pragma("unroll")                                                    \
            for (int r = 0; r < 4; ++r) {                                        \
                const float ev = __expf(acc1[nt][r] * rn[r]);                    \
                e[nt][r] = valid ? ev : 0.f;                                     \
                d[r] += e[nt][r];                                                \
            }                                                                    \
        }                                                                        \
        _Pragma("unroll")                                                        \
        for (int r = 0; r < 4; ++r) {                                            \
            d[r] += __shfl_xor(d[r], 1);                                         \
            d[r] += __shfl_xor(d[r], 2);                                         \
            d[r] += __shfl_xor(d[r], 4);                                         \
            d[r] += __shfl_xor(d[r], 8);                                         \
            d[r] = 1.f / d[r];                                                   \
        }                                                                        \
        _Pragma("unroll")                                                        \
        for (int nt = 0; nt < 4; ++nt) {                                         \
            bf16x4v sv;                                                          \
            float ap = 0.f;                                                      \
            _Pragma("unroll")                                                    \
            for (int r = 0; r < 4; ++r) {                                        \
                const float s = e[nt][r] * d[r];                                 \
                ap += s;                                                         \
                sv[r] = (__bf16)(s * rn[r]);                                     \
            }                                                                    \
            asum_acc[nt] += ap;                                                  \
            *(bf16x4v*)&st[p][(16 * nt + l15) * P2 + 16 * wv + 4 * q] = sv;      \
        }                                                                        \
        __syncthreads();               /* barrier B: st[p] ready */              \
        {                                                                        \
            const int clp = wv >> 1;                                             \
            const int chh = wv & 1;                                              \
            bf16x8v sa[2][2];                                                    \
            _Pragma("unroll")                                                    \
            for (int clb = 0; clb < 2; ++clb)                                    \
                _Pragma("unroll")                                                \
                for (int ks2 = 0; ks2 < 2; ++ks2)                                \
                    sa[clb][ks2] = *(const bf16x8v*)                             \
                        &st[p][(16 * (2 * clp + clb) + l15) * P2                 \
                               + 32 * ks2 + 8 * q];                              \
            _Pragma("unroll")                                                    \
            for (int cb = 0; cb < 4; ++cb) {                                     \
                const int c = 16 * (4 * chh + cb) + l15;                         \
                const bf16x8v xf0 = *(const bf16x8v*)&xb[p][c * P1 + 8 * q];     \
                const bf16x8v xf1 = *(const bf16x8v*)&xb[p][c * P1 + 32 + 8 * q];\
                acc2[cb]     = MFMA(sa[0][0], xf0, acc2[cb]);                    \
                acc2[cb]     = MFMA(sa[0][1], xf1, acc2[cb]);                    \
                acc2[4 + cb] = MFMA(sa[1][0], xf0, acc2[4 + cb]);                \
                acc2[4 + cb] = MFMA(sa[1][1], xf1, acc2[4 + cb]);                \
            }                                                                    \
        }                                                                        \
        p ^= 1;                                                                  \
    }

__global__ __launch_bounds__(256, 2)
void k_main(const float* __restrict__ x, const float* __restrict__ conv_w,
            float* __restrict__ gaccp, float* __restrict__ gasump)
{
    __shared__ __align__(16) __bf16 xb[2][C_ * P1];   // 2 x 18432 B  x bf16 [c][t]
    __shared__ __align__(16) __bf16 st[2][K_ * P2];   // 2 x  9216 B  soft*rn [cl][t]
    __shared__ float asq[4 * K_];                     // a_sum partials

    const int tid  = threadIdx.x;
    const int lane = tid & 63;
    const int wv   = __builtin_amdgcn_readfirstlane(tid >> 6);
    const int q    = lane >> 4;
    const int l15  = lane & 15;
    const int n     = blockIdx.x >> 5;
    const int chunk = blockIdx.x & 31;
    const int t0    = chunk * CT;

    // ---- preload W B-fragments: wf[nt][ks], cl = 16nt+l15, c = 32ks+8q+j ----
    bf16x8v wf[5][4];
#pragma unroll
    for (int nt = 0; nt < 5; ++nt) {
        const int row = min(16 * nt + l15, KG_ - 1);   // ghost rows >=73 masked later
#pragma unroll
        for (int ks = 0; ks < 4; ++ks) {
            const float* wp = conv_w + (size_t)row * C_ + 32 * ks + 8 * q;
            const float4 w0 = *(const float4*)wp;
            const float4 w1 = *(const float4*)(wp + 4);
            bf16x8v f;
            f[0] = (__bf16)w0.x; f[1] = (__bf16)w0.y; f[2] = (__bf16)w0.z; f[3] = (__bf16)w0.w;
            f[4] = (__bf16)w1.x; f[5] = (__bf16)w1.y; f[6] = (__bf16)w1.z; f[7] = (__bf16)w1.w;
            wf[nt][ks] = f;
        }
    }

    f32x4v acc2[8];                    // VLAD accumulators: 2 cl-blocks x 4 c-blocks
#pragma unroll
    for (int i = 0; i < 8; ++i) acc2[i] = (f32x4v){0.f, 0.f, 0.f, 0.f};
    float asum_acc[4] = {0.f, 0.f, 0.f, 0.f};

    // staging: thread covers (c = cst+16r, t = 4*t4..4*t4+3), r = 0..7
    const int cst = tid >> 4, t4 = tid & 15;
    const float* xbase = x + ((size_t)(n * C_ + cst)) * T_ + 4 * t4;

    // GEMM1 A-frag LDS t-index: lane reads xb[32ks+8q+j][16wv+l15]
    const int tA = 16 * wv + l15;

    // paired prefetch: pfA = tile 2ip, pfB = tile 2ip+1. Per row, the wave's
    // A+B requests are adjacent 256-B segments -> 512-B contiguous bursts.
    float4 pfA[8], pfB[8];
#pragma unroll
    for (int r = 0; r < 8; ++r) {
        pfA[r] = *(const float4*)(xbase + (size_t)r * 16 * T_ + t0);
        pfB[r] = *(const float4*)(xbase + (size_t)r * 16 * T_ + t0 + 64);
    }

    int p = 0;
    for (int ip = 0; ip < 4; ++ip) {
        TILE_BODY(pfA, false)          // tile 2ip
        TILE_BODY(pfB, true)           // tile 2ip+1 (+ next-pair prefetch)
    }

    // ---- write per-chunk VLAD partials (plain stores, no atomics) ----
    {
        const int clp = wv >> 1, chh = wv & 1;
        float* gp = gaccp + ((size_t)(n * NCH + chunk) * K_) * C_;
#pragma unroll
        for (int clb = 0; clb < 2; ++clb)
#pragma unroll
            for (int cb = 0; cb < 4; ++cb)
#pragma unroll
                for (int r = 0; r < 4; ++r) {
                    const int cl = 16 * (2 * clp + clb) + 4 * q + r;
                    const int c  = 16 * (4 * chh + cb) + l15;
                    gp[cl * C_ + c] = acc2[clb * 4 + cb][r];
                }
    }

    // ---- a_sum per-chunk partials ----
#pragma unroll
    for (int nt = 0; nt < 4; ++nt) {
        float v = asum_acc[nt];
        v += __shfl_xor(v, 16);
        v += __shfl_xor(v, 32);
        if (q == 0) asq[wv * K_ + 16 * nt + l15] = v;
    }
    __syncthreads();
    if (tid < K_) {
        const float s = asq[tid] + asq[K_ + tid] + asq[2 * K_ + tid] + asq[3 * K_ + tid];
        gasump[(n * NCH + chunk) * K_ + tid] = s;
    }
}

// ---------------------------------------------------------------------------
// Kernel 2: reduce chunk partials, centroid subtract, intra-norm, *cw.
//   Writes FINAL output. The reference's last global L2-normalize is a
//   mathematical identity: after intra-norm each cluster vector is unit-norm,
//   scaled by cwn_k = cw_k/||cw||, so ||v||^2 = sum_k cwn_k^2 = 1 exactly.
// ---------------------------------------------------------------------------
__global__ __launch_bounds__(256)
void k_post(const float* __restrict__ gaccp, const float* __restrict__ gasump,
            const float* __restrict__ centroids, const float* __restrict__ cwv,
            float* __restrict__ out)
{
    __shared__ float red[4][C_];    // per-wave vlad partials
    __shared__ float reda[4];       // per-wave a_sum partials

    const int b = blockIdx.x;       // n*64 + k
    const int n = b >> 6, k = b & 63;
    const int tid  = threadIdx.x;
    const int lane = tid & 63;
    const int wv   = tid >> 6;

    // hoisted epilogue inputs (independent of partials; overlap their latency)
    const float cv = cwv[lane];
    float cs = cv * cv;
#pragma unroll
    for (int off = 32; off; off >>= 1) cs += __shfl_xor(cs, off);
    const float cwn = cwv[k] / fmaxf(sqrtf(cs), EPSN);
    const float* ce = centroids + (size_t)k * C_;
    const float ce0 = ce[lane];
    const float ce1 = ce[lane + 64];

    // each wave sums its 8 chunks; lane covers c = 2*lane, 2*lane+1
    float2 v = {0.f, 0.f};
    float asum = 0.f;
    const float* gp = gaccp + ((size_t)(n * NCH + wv * 8) * K_ + k) * C_ + 2 * lane;
    const float* gs = gasump + (size_t)(n * NCH + wv * 8) * K_ + k;
#pragma unroll
    for (int ch = 0; ch < 8; ++ch) {
        const float2 g = *(const float2*)gp;
        v.x += g.x; v.y += g.y;
        asum += gs[ch * K_];
        gp += (size_t)K_ * C_;
    }
    red[wv][2 * lane]     = v.x;
    red[wv][2 * lane + 1] = v.y;
    if (lane == 0) reda[wv] = asum;
    __syncthreads();

    if (wv == 0) {
        float v0 = red[0][lane]      + red[1][lane]      + red[2][lane]      + red[3][lane];
        float v1 = red[0][lane + 64] + red[1][lane + 64] + red[2][lane + 64] + red[3][lane + 64];
        const float as = reda[0] + reda[1] + reda[2] + reda[3];

        v0 -= as * ce0;
        v1 -= as * ce1;
        float ss = v0 * v0 + v1 * v1;
#pragma unroll
        for (int off = 32; off; off >>= 1) ss += __shfl_xor(ss, off);
        const float scale = cwn / fmaxf(sqrtf(ss), EPSN);

        float* o = out + (size_t)n * (K_ * C_) + (size_t)k * C_;
        o[lane]      = v0 * scale;
        o[lane + 64] = v1 * scale;
    }
}

// ---------------------------------------------------------------------------
extern "C" void kernel_launch(void* const* d_in, const int* in_sizes, int n_in,
                              void* d_out, int out_size, void* d_ws, size_t ws_size,
                              hipStream_t stream)
{
    const float* x         = (const float*)d_in[0];
    const float* conv_w    = (const float*)d_in[1];
    const float* centroids = (const float*)d_in[2];
    const float* cweights  = (const float*)d_in[3];
    float* out = (float*)d_out;

    float* gasump = (float*)d_ws;                    // [16*32][64]
    float* gaccp  = gasump + N_ * NCH * K_;          // [16*32][64][128] = 16 MB

    hipLaunchKernelGGL(k_main, dim3(N_ * NCH), dim3(256), 0, stream,
                       x, conv_w, gaccp, gasump);
    hipLaunchKernelGGL(k_post, dim3(N_ * K_), dim3(256), 0, stream,
                       gaccp, gasump, centroids, cweights, out);
}

// Round 10
// 209.046 us; speedup vs baseline: 1.0224x; 1.0224x over previous
//
#include <hip/hip_runtime.h>
#include <math.h>

#define N_  16
#define C_  128
#define T_  16384
#define K_  64
#define KG_ 73
#define CT  512           // t-chunk per block -> 512 blocks = 2 blocks/CU
#define NCH 32            // chunks per n
#define EPSN 1e-12f
#define P1  72            // xb pitch (bf16): 36 dwords -> 8 bank-groups for b128 reads
#define P2  72            // st pitch (bf16)

typedef __bf16 bf16x4v __attribute__((ext_vector_type(4)));
typedef __bf16 bf16x8v __attribute__((ext_vector_type(8)));
typedef float  f32x4v  __attribute__((ext_vector_type(4)));

#define MFMA(a, b, c) __builtin_amdgcn_mfma_f32_16x16x32_bf16((a), (b), (c), 0, 0, 0)

// LDS-only barrier: drains ds ops (producer->consumer visibility within CU)
// WITHOUT the vmcnt(0) drain __syncthreads emits. Keeps the pf HBM prefetch
// in flight across the barrier until its true use (next tile's staging).
#define BAR_LGKM()                                          \
    do {                                                    \
        asm volatile("s_waitcnt lgkmcnt(0)" ::: "memory");  \
        __builtin_amdgcn_s_barrier();                       \
    } while (0)

// ---------------------------------------------------------------------------
// Kernel 1: fused normalize -> logits (MFMA) -> softmax -> VLAD (MFMA) ->
//           per-chunk partials (NO atomics).
// R9 change (T4): in-loop __syncthreads -> lgkmcnt-only raw s_barrier.
// __syncthreads emits s_waitcnt vmcnt(0) before s_barrier, force-draining
// the 8 HBM prefetch loads ~500cy after issue (HBM latency ~900cy under
// load) — 16x per block. All in-loop cross-wave deps are LDS (xb/st), so
// lgkmcnt(0)+s_barrier is sufficient; buffer reuse is 2 barriers apart.
// GEMM1 A-frags from LDS (R6): GEMM1 has no vmem dependency at all.
// ---------------------------------------------------------------------------
__global__ __launch_bounds__(256, 2)
void k_main(const float* __restrict__ x, const float* __restrict__ conv_w,
            float* __restrict__ gaccp, float* __restrict__ gasump)
{
    __shared__ __align__(16) __bf16 xb[2][C_ * P1];   // 2 x 18432 B  x bf16 [c][t]
    __shared__ __align__(16) __bf16 st[2][K_ * P2];   // 2 x  9216 B  soft*rn [cl][t]
    __shared__ float asq[4 * K_];                     // a_sum partials

    const int tid  = threadIdx.x;
    const int lane = tid & 63;
    const int wv   = __builtin_amdgcn_readfirstlane(tid >> 6);
    const int q    = lane >> 4;
    const int l15  = lane & 15;
    const int n     = blockIdx.x >> 5;
    const int chunk = blockIdx.x & 31;
    const int t0    = chunk * CT;

    // ---- preload W B-fragments: wf[nt][ks], cl = 16nt+l15, c = 32ks+8q+j ----
    bf16x8v wf[5][4];
#pragma unroll
    for (int nt = 0; nt < 5; ++nt) {
        const int row = min(16 * nt + l15, KG_ - 1);   // ghost rows >=73 masked later
#pragma unroll
        for (int ks = 0; ks < 4; ++ks) {
            const float* wp = conv_w + (size_t)row * C_ + 32 * ks + 8 * q;
            const float4 w0 = *(const float4*)wp;
            const float4 w1 = *(const float4*)(wp + 4);
            bf16x8v f;
            f[0] = (__bf16)w0.x; f[1] = (__bf16)w0.y; f[2] = (__bf16)w0.z; f[3] = (__bf16)w0.w;
            f[4] = (__bf16)w1.x; f[5] = (__bf16)w1.y; f[6] = (__bf16)w1.z; f[7] = (__bf16)w1.w;
            wf[nt][ks] = f;
        }
    }

    f32x4v acc2[8];                    // VLAD accumulators: 2 cl-blocks x 4 c-blocks
#pragma unroll
    for (int i = 0; i < 8; ++i) acc2[i] = (f32x4v){0.f, 0.f, 0.f, 0.f};
    float asum_acc[4] = {0.f, 0.f, 0.f, 0.f};

    // staging: thread covers (c = cst+16r, t = 4*t4..4*t4+3), r = 0..7
    const int cst = tid >> 4, t4 = tid & 15;
    const float* xbase = x + ((size_t)(n * C_ + cst)) * T_ + 4 * t4;

    // GEMM1 A-frag LDS t-index: lane reads xb[32ks+8q+j][16wv+l15]
    const int tA = 16 * wv + l15;

    float4 pf[8];
#pragma unroll
    for (int r = 0; r < 8; ++r)
        pf[r] = *(const float4*)(xbase + (size_t)r * 16 * T_ + t0);

    int p = 0;
    for (int it = 0; it < 8; ++it) {
        // ---- stage prefetched tile -> xb[p] (bf16, b64 writes) ----
        // (compiler inserts the vmcnt wait for pf here, at true use)
#pragma unroll
        for (int r = 0; r < 8; ++r) {
            bf16x4v v = { (__bf16)pf[r].x, (__bf16)pf[r].y, (__bf16)pf[r].z, (__bf16)pf[r].w };
            *(bf16x4v*)&xb[p][(cst + 16 * r) * P1 + 4 * t4] = v;
        }
        BAR_LGKM();                          // barrier A: xb[p] visible (LDS only)

        // ---- prefetch next tile (HBM; stays in flight across barrier B) ----
        if (it < 7) {
            const int tb = t0 + (it + 1) * 64;
#pragma unroll
            for (int r = 0; r < 8; ++r)
                pf[r] = *(const float4*)(xbase + (size_t)r * 16 * T_ + tb);
        }

        // ---- GEMM1 + Gram, A-frags from LDS (lgkmcnt; vmcnt-free) ----
        f32x4v acc1[5];
#pragma unroll
        for (int i = 0; i < 5; ++i) acc1[i] = (f32x4v){0.f, 0.f, 0.f, 0.f};
        f32x4v gr = (f32x4v){0.f, 0.f, 0.f, 0.f};

#pragma unroll
        for (int ks = 0; ks < 4; ++ks) {
            bf16x8v af;
#pragma unroll
            for (int j = 0; j < 8; ++j)
                af[j] = xb[p][(32 * ks + 8 * q + j) * P1 + tA];
            gr = MFMA(af, af, gr);
#pragma unroll
            for (int nt = 0; nt < 5; ++nt)
                acc1[nt] = MFMA(af, wf[nt][ks], acc1[nt]);
        }

        // ---- rn_t from Gram diag via bpermute (t = 16wv + 4q + r) ----
        float rn[4];
#pragma unroll
        for (int r = 0; r < 4; ++r) {
            const float ss = __int_as_float(
                __builtin_amdgcn_ds_bpermute((20 * q + r) << 2, __float_as_int(gr[r])));
            rn[r] = 1.f / fmaxf(sqrtf(ss), EPSN);
        }

        // ---- softmax over 73 clusters, fully in registers ----
        float e[5][4];
        float d[4] = {0.f, 0.f, 0.f, 0.f};
#pragma unroll
        for (int nt = 0; nt < 5; ++nt) {
            const bool valid = (16 * nt + l15) < KG_;
#pragma unroll
            for (int r = 0; r < 4; ++r) {
                const float ev = __expf(acc1[nt][r] * rn[r]);   // |logit| <= ~13
                e[nt][r] = valid ? ev : 0.f;
                d[r] += e[nt][r];
            }
        }
#pragma unroll
        for (int r = 0; r < 4; ++r) {
            d[r] += __shfl_xor(d[r], 1);
            d[r] += __shfl_xor(d[r], 2);
            d[r] += __shfl_xor(d[r], 4);
            d[r] += __shfl_xor(d[r], 8);
            d[r] = 1.f / d[r];
        }

        // ---- soft -> st[p][cl][t] (rn folded), a_sum accumulate (fp32) ----
#pragma unroll
        for (int nt = 0; nt < 4; ++nt) {
            bf16x4v sv;
            float ap = 0.f;
#pragma unroll
            for (int r = 0; r < 4; ++r) {
                const float s = e[nt][r] * d[r];
                ap += s;
                sv[r] = (__bf16)(s * rn[r]);
            }
            asum_acc[nt] += ap;
            *(bf16x4v*)&st[p][(16 * nt + l15) * P2 + 16 * wv + 4 * q] = sv;
        }
        BAR_LGKM();                          // barrier B: st[p] ready (LDS only)

        // ---- GEMM2: wave covers 2 cl-blocks x 4 c-blocks ----
        {
            const int clp = wv >> 1;         // cl pair: blocks {2clp, 2clp+1}
            const int chh = wv & 1;          // c half:  blocks {4chh..4chh+3}
            bf16x8v sa[2][2];
#pragma unroll
            for (int clb = 0; clb < 2; ++clb)
#pragma unroll
                for (int ks2 = 0; ks2 < 2; ++ks2)
                    sa[clb][ks2] = *(const bf16x8v*)
                        &st[p][(16 * (2 * clp + clb) + l15) * P2 + 32 * ks2 + 8 * q];
#pragma unroll
            for (int cb = 0; cb < 4; ++cb) {
                const int c = 16 * (4 * chh + cb) + l15;
                const bf16x8v xf0 = *(const bf16x8v*)&xb[p][c * P1 + 8 * q];
                const bf16x8v xf1 = *(const bf16x8v*)&xb[p][c * P1 + 32 + 8 * q];
                acc2[cb]     = MFMA(sa[0][0], xf0, acc2[cb]);
                acc2[cb]     = MFMA(sa[0][1], xf1, acc2[cb]);
                acc2[4 + cb] = MFMA(sa[1][0], xf0, acc2[4 + cb]);
                acc2[4 + cb] = MFMA(sa[1][1], xf1, acc2[4 + cb]);
            }
        }
        p ^= 1;
    }

    // ---- write per-chunk VLAD partials (plain stores, no atomics) ----
    {
        const int clp = wv >> 1, chh = wv & 1;
        float* gp = gaccp + ((size_t)(n * NCH + chunk) * K_) * C_;
#pragma unroll
        for (int clb = 0; clb < 2; ++clb)
#pragma unroll
            for (int cb = 0; cb < 4; ++cb)
#pragma unroll
                for (int r = 0; r < 4; ++r) {
                    const int cl = 16 * (2 * clp + clb) + 4 * q + r;
                    const int c  = 16 * (4 * chh + cb) + l15;
                    gp[cl * C_ + c] = acc2[clb * 4 + cb][r];
                }
    }

    // ---- a_sum per-chunk partials (full __syncthreads: epilogue, one-time) ----
#pragma unroll
    for (int nt = 0; nt < 4; ++nt) {
        float v = asum_acc[nt];
        v += __shfl_xor(v, 16);
        v += __shfl_xor(v, 32);
        if (q == 0) asq[wv * K_ + 16 * nt + l15] = v;
    }
    __syncthreads();
    if (tid < K_) {
        const float s = asq[tid] + asq[K_ + tid] + asq[2 * K_ + tid] + asq[3 * K_ + tid];
        gasump[(n * NCH + chunk) * K_ + tid] = s;
    }
}

// ---------------------------------------------------------------------------
// Kernel 2: reduce chunk partials, centroid subtract, intra-norm, *cw.
//   Writes FINAL output. The reference's last global L2-normalize is a
//   mathematical identity: after intra-norm each cluster vector is unit-norm,
//   scaled by cwn_k = cw_k/||cw||, so ||v||^2 = sum_k cwn_k^2 = 1 exactly.
// ---------------------------------------------------------------------------
__global__ __launch_bounds__(256)
void k_post(const float* __restrict__ gaccp, const float* __restrict__ gasump,
            const float* __restrict__ centroids, const float* __restrict__ cwv,
            float* __restrict__ out)
{
    __shared__ float red[4][C_];    // per-wave vlad partials
    __shared__ float reda[4];       // per-wave a_sum partials

    const int b = blockIdx.x;       // n*64 + k
    const int n = b >> 6, k = b & 63;
    const int tid  = threadIdx.x;
    const int lane = tid & 63;
    const int wv   = tid >> 6;

    // hoisted epilogue inputs (independent of partials; overlap their latency)
    const float cv = cwv[lane];
    float cs = cv * cv;
#pragma unroll
    for (int off = 32; off; off >>= 1) cs += __shfl_xor(cs, off);
    const float cwn = cwv[k] / fmaxf(sqrtf(cs), EPSN);
    const float* ce = centroids + (size_t)k * C_;
    const float ce0 = ce[lane];
    const float ce1 = ce[lane + 64];

    // each wave sums its 8 chunks; lane covers c = 2*lane, 2*lane+1
    float2 v = {0.f, 0.f};
    float asum = 0.f;
    const float* gp = gaccp + ((size_t)(n * NCH + wv * 8) * K_ + k) * C_ + 2 * lane;
    const float* gs = gasump + (size_t)(n * NCH + wv * 8) * K_ + k;
#pragma unroll
    for (int ch = 0; ch < 8; ++ch) {
        const float2 g = *(const float2*)gp;
        v.x += g.x; v.y += g.y;
        asum += gs[ch * K_];
        gp += (size_t)K_ * C_;
    }
    red[wv][2 * lane]     = v.x;
    red[wv][2 * lane + 1] = v.y;
    if (lane == 0) reda[wv] = asum;
    __syncthreads();

    if (wv == 0) {
        float v0 = red[0][lane]      + red[1][lane]      + red[2][lane]      + red[3][lane];
        float v1 = red[0][lane + 64] + red[1][lane + 64] + red[2][lane + 64] + red[3][lane + 64];
        const float as = reda[0] + reda[1] + reda[2] + reda[3];

        v0 -= as * ce0;
        v1 -= as * ce1;
        float ss = v0 * v0 + v1 * v1;
#pragma unroll
        for (int off = 32; off; off >>= 1) ss += __shfl_xor(ss, off);
        const float scale = cwn / fmaxf(sqrtf(ss), EPSN);

        float* o = out + (size_t)n * (K_ * C_) + (size_t)k * C_;
        o[lane]      = v0 * scale;
        o[lane + 64] = v1 * scale;
    }
}

// ---------------------------------------------------------------------------
extern "C" void kernel_launch(void* const* d_in, const int* in_sizes, int n_in,
                              void* d_out, int out_size, void* d_ws, size_t ws_size,
                              hipStream_t stream)
{
    const float* x         = (const float*)d_in[0];
    const float* conv_w    = (const float*)d_in[1];
    const float* centroids = (const float*)d_in[2];
    const float* cweights  = (const float*)d_in[3];
    float* out = (float*)d_out;

    float* gasump = (float*)d_ws;                    // [16*32][64]
    float* gaccp  = gasump + N_ * NCH * K_;          // [16*32][64][128] = 16 MB

    hipLaunchKernelGGL(k_main, dim3(N_ * NCH), dim3(256), 0, stream,
                       x, conv_w, gaccp, gasump);
    hipLaunchKernelGGL(k_post, dim3(N_ * K_), dim3(256), 0, stream,
                       gaccp, gasump, centroids, cweights, out);
}